// Round 15
// baseline (47.579 us; speedup 1.0000x reference)
//
#include <hip/hip_runtime.h>
#include <hip/hip_bf16.h>

#define HDIM 2048
#define HH (HDIM * HDIM)          // 4,194,304 pixels per plane
#define NBINS 256
#define KCNT 1048576.0f           // K_SRC == K_TAR == HH/4 (exactly 2^20)
#define TOTAL_ELEMS 12582912.0    // 3 * H * H

#define NBLK 2048                 // 2048 blocks x 256 thr x 8 px = 4.19M px, one shot
// src pack: bits [31:20] = count, bits [19:0] = sum(frac * 2^12, trunc).
// Per block (2048 px): peak mid-bin count ~30 << 4095; fracsum << 2^20.
// Trunc bias on output ~3e-5 (threshold 2e-3).
#define FRAC_SCALE 4096.0f
#define FRAC_INV   (1.0 / 4096.0)

// Per-block partial row: [0,768) u32 packed src, [768,1536) u32 tar counts.
#define ROW_DWORDS 1536
#define ROW_BYTES  6144
// tail: counts[1536] + fracsI[768]
#define TAIL_WORDS 2304
#define ROWS_PER_CHUNK 32

typedef float floatx4 __attribute__((ext_vector_type(4)));

__device__ __forceinline__ floatx4 nt_load4(const float* p) {
    return __builtin_nontemporal_load((const floatx4*)p);
}

// Kernel 1: per-block histograms, ONE-SHOT: each thread owns 8 contiguous px
// and issues all 16 float4 loads (masks cached, data non-temporal) before the
// bin/atomic phase — maximum in-flight read bytes per wave, zero loop
// re-issue latency. NT on the 6 congruent data planes (no-reuse streams);
// masks stay cacheable/L3-resident. Block 0 zeroes the accumulator tail.
__global__ void __launch_bounds__(256) hist_kernel(
        const float* __restrict__ inp,
        const float* __restrict__ tar,
        const float* __restrict__ msrc,
        const float* __restrict__ mtar,
        unsigned int* __restrict__ parts,
        unsigned int* __restrict__ tail) {
    __shared__ unsigned int hs[3 * NBINS];   // src packed count|fracsum
    __shared__ unsigned int ht[3 * NBINS];   // tar counts
    for (int i = threadIdx.x; i < 3 * NBINS; i += blockDim.x) {
        hs[i] = 0u;
        ht[i] = 0u;
    }
    if (blockIdx.x == 0)
        for (int i = threadIdx.x; i < TAIL_WORDS; i += blockDim.x)
            tail[i] = 0u;
    __syncthreads();

    const int p8 = blockIdx.x * 256 + threadIdx.x;     // 8-px tile index
    const size_t f0 = (size_t)p8 * 2;                  // float4 index, +0/+1

    // ---- issue ALL loads up front ----
    const float4 ms0 = ((const float4*)msrc)[f0];
    const float4 ms1 = ((const float4*)msrc)[f0 + 1];
    const float4 mt0 = ((const float4*)mtar)[f0];
    const float4 mt1 = ((const float4*)mtar)[f0 + 1];
    floatx4 v[3][2], w[3][2];
    #pragma unroll
    for (int c = 0; c < 3; ++c) {
        const float* ip = inp + (size_t)c * HH;
        const float* tp = tar + (size_t)c * HH;
        v[c][0] = nt_load4(ip + f0 * 4);
        v[c][1] = nt_load4(ip + f0 * 4 + 4);
        w[c][0] = nt_load4(tp + f0 * 4);
        w[c][1] = nt_load4(tp + f0 * 4 + 4);
    }
    const float mk[8] = {ms0.x, ms0.y, ms0.z, ms0.w, ms1.x, ms1.y, ms1.z, ms1.w};
    const float tk[8] = {mt0.x, mt0.y, mt0.z, mt0.w, mt1.x, mt1.y, mt1.z, mt1.w};

    int nf[6] = {0, 0, 0, 0, 0, 0};   // v==255 counts (rows 0-2 src, 3-5 tar)

    #pragma unroll
    for (int c = 0; c < 3; ++c) {
        #pragma unroll
        for (int k = 0; k < 8; ++k) {
            const float xv = v[c][k >> 2][k & 3];
            const float xw = w[c][k >> 2][k & 3];
            // --- src: one packed atomic for mid bins ---
            {
                const bool on = (mk[k] != 0.0f);
                const float vr   = (xv + 1.0f) * 0.5f;
                const float v255 = fminf(fmaxf(vr, 0.0f), 1.0f) * 255.0f;
                const bool hi = (v255 >= 255.0f);
                const bool lo = (v255 <= 0.0f);
                nf[c] += (int)(on && hi);
                if (on && !lo && !hi) {
                    const int b = (int)v255;            // 0..254
                    const unsigned fx =
                        (unsigned)((v255 - (float)b) * FRAC_SCALE);
                    atomicAdd(&hs[c * NBINS + b], (1u << 20) | fx);
                }
            }
            // --- tar: counts only ---
            {
                const bool on = (tk[k] != 0.0f);
                const float vr   = (xw + 1.0f) * 0.5f;
                const float v255 = fminf(fmaxf(vr, 0.0f), 1.0f) * 255.0f;
                const bool hi = (v255 >= 255.0f);
                const bool lo = (v255 <= 0.0f);
                nf[3 + c] += (int)(on && hi);
                if (on && !lo && !hi)
                    atomicAdd(&ht[c * NBINS + (int)v255], 1u);
            }
        }
    }

    // wave-reduce the 6 clip-255 counters, one LDS atomic per wave each
    const int lane = threadIdx.x & 63;
    #pragma unroll
    for (int j = 0; j < 6; ++j) {
        int f = nf[j];
        #pragma unroll
        for (int off = 32; off > 0; off >>= 1)
            f += __shfl_down(f, off, 64);
        if (lane == 0 && f) {
            if (j < 3) atomicAdd(&hs[j * NBINS + NBINS - 1], ((unsigned)f) << 20);
            else       atomicAdd(&ht[(j - 3) * NBINS + NBINS - 1], (unsigned)f);
        }
    }
    __syncthreads();

    // coalesced flush of this block's partial row (full overwrite -> no memset)
    unsigned int* row = parts + (size_t)blockIdx.x * ROW_DWORDS;
    for (int i = threadIdx.x; i < ROW_DWORDS; i += blockDim.x)
        row[i] = (i < 3 * NBINS) ? hs[i] : ht[i - 3 * NBINS];
}

// Kernel 2: column reduction over row-chunks; all-integer atomics
// (deterministic). Separate dispatch — R12's fused last-block variant
// measured ~11 us slower.
__global__ void reduce_kernel(const unsigned int* __restrict__ parts,
                              int* __restrict__ counts,      // [1536]
                              int* __restrict__ fracsI) {    // [768]
    const int j = blockIdx.x * blockDim.x + threadIdx.x;   // column 0..1535
    const int w0 = blockIdx.y * ROWS_PER_CHUNK;
    const int w1 = w0 + ROWS_PER_CHUNK;                    // NBLK % 32 == 0

    if (j < 768) {
        unsigned cnt = 0, fr = 0;
        for (int w = w0; w < w1; ++w) {
            const unsigned p = parts[(size_t)w * ROW_DWORDS + j];
            cnt += p >> 20;
            fr  += p & 0xFFFFFu;
        }
        if (cnt) atomicAdd(&counts[j], (int)cnt);
        if (fr)  atomicAdd(&fracsI[j], (int)fr);
    } else {
        unsigned cnt = 0;
        for (int w = w0; w < w1; ++w)
            cnt += parts[(size_t)w * ROW_DWORDS + j];
        if (cnt) atomicAdd(&counts[j], (int)cnt);
    }
}

// Kernel 3: derive n_0 per row (mask totals are exactly 2^20), cdf (bit-exact
// serial f32 cumsum), searchsorted table, analytic loss:
//   t <= b : sum = s_b - n_b*t ;  t >= b+1 : sum = n_b*t - s_b,
// with s_b = n_b*b + F_b, F_b = fracsI_b * 2^-12 (0 for clip bins).
__global__ void final_kernel(const int* __restrict__ counts,
                             const int* __restrict__ fracsI,
                             float* __restrict__ out) {
    __shared__ float cdf[6][NBINS];
    __shared__ int   lcnt[6 * NBINS];
    __shared__ double red[12];
    const int tid = threadIdx.x;           // 768 threads
    lcnt[tid]       = counts[tid];
    lcnt[tid + 768] = counts[tid + 768];
    __syncthreads();

    if (tid < 6) {
        // true n_0 = 2^20 - sum(b>=1); lcnt[..+0] holds only mid-bin-0 atomics
        int tot = 0;
        for (int i = 1; i < NBINS; ++i) tot += lcnt[tid * NBINS + i];
        lcnt[tid * NBINS + 0] = (1 << 20) - tot;
        // pdf = count / 2^20 is exact; serial f32 cumsum matches the reference
        float run = 0.0f;
        for (int i = 0; i < NBINS; ++i) {
            run += (float)lcnt[tid * NBINS + i] * (1.0f / KCNT);
            cdf[tid][i] = run;
        }
    }
    __syncthreads();

    const int c = tid >> 8, b = tid & (NBINS - 1);
    const float d = cdf[c][b];
    const float* r = cdf[3 + c];
    // searchsorted(r, d, side='left'): first j with r[j] >= d
    int lo = 0, hi = NBINS;
    while (lo < hi) {
        int mid = (lo + hi) >> 1;
        if (r[mid] < d) lo = mid + 1; else hi = mid;
    }
    int j = lo;
    if (j < 1) j = 1;
    if (j > NBINS - 1) j = NBINS - 1;
    bool valid = (r[j - 1] <= d) && (d <= r[j]);
    int t = valid ? j : b;
    if (b == NBINS - 1) t = NBINS - 1;

    const int n = lcnt[c * NBINS + b];
    const double s = (double)n * (double)b
                   + (double)fracsI[c * NBINS + b] * FRAC_INV;
    double contrib = (t <= b) ? (s - (double)n * (double)t)
                              : ((double)n * (double)t - s);

    #pragma unroll
    for (int off = 32; off > 0; off >>= 1)
        contrib += __shfl_down(contrib, off, 64);
    const int wave = tid >> 6, lane = tid & 63;
    if (lane == 0) red[wave] = contrib;
    __syncthreads();
    if (tid == 0) {
        double tot = 0.0;
        for (int w = 0; w < 12; ++w) tot += red[w];
        out[0] = (float)(tot / TOTAL_ELEMS);
    }
}

extern "C" void kernel_launch(void* const* d_in, const int* in_sizes, int n_in,
                              void* d_out, int out_size, void* d_ws, size_t ws_size,
                              hipStream_t stream) {
    const float* inp  = (const float*)d_in[0];   // (1,3,H,H)
    const float* tar  = (const float*)d_in[1];   // (1,3,H,H)
    const float* msrc = (const float*)d_in[2];   // (1,1,H,H)
    const float* mtar = (const float*)d_in[3];   // (1,1,H,H)
    float* out = (float*)d_out;

    char* ws = (char*)d_ws;
    unsigned int* parts  = (unsigned int*)ws;
    unsigned int* tail   = (unsigned int*)(ws + (size_t)NBLK * ROW_BYTES);
    int*          counts = (int*)tail;                 // [1536]
    int*          fracsI = (int*)(tail + 1536);        // [768]

    hist_kernel<<<NBLK, 256, 0, stream>>>(inp, tar, msrc, mtar, parts, tail);

    dim3 rgrid(ROW_DWORDS / 256, NBLK / ROWS_PER_CHUNK);   // 6 x 64 = 384
    reduce_kernel<<<rgrid, 256, 0, stream>>>(parts, counts, fracsI);
    final_kernel<<<1, 3 * NBINS, 0, stream>>>(counts, fracsI, out);
}

// Round 16
// 44.378 us; speedup vs baseline: 1.0721x; 1.0721x over previous
//
#include <hip/hip_runtime.h>
#include <hip/hip_bf16.h>

#define HDIM 2048
#define HH (HDIM * HDIM)          // 4,194,304 pixels per plane
#define NBINS 256
#define KCNT 1048576.0f           // K_SRC == K_TAR == HH/4 (exactly 2^20)
#define TOTAL_ELEMS 12582912.0    // 3 * H * H

#define NBLK 1024                 // R14 winner shape: 4 grid-stride iterations
// src pack: bits [31:20] = count, bits [19:0] = sum(frac * 2^12, trunc).
// Per block (4096 px): peak mid-bin count ~60 << 4095; fracsum << 2^20.
// Trunc bias on output ~3e-5 (threshold 2e-3).
#define FRAC_SCALE 4096.0f
#define FRAC_INV   (1.0 / 4096.0)

// Per-block partial row: [0,768) u32 packed src, [768,1536) u32 tar counts.
#define ROW_DWORDS 1536
#define ROW_BYTES  6144
// tail: counts[1536] + fracsI[768]
#define TAIL_WORDS 2304
#define ROWS_PER_CHUNK 32

typedef float floatx4 __attribute__((ext_vector_type(4)));

__device__ __forceinline__ floatx4 nt_load4(const float* p) {
    return __builtin_nontemporal_load((const floatx4*)p);
}

#if __has_builtin(__builtin_amdgcn_global_load_lds)
#define HAVE_DMA 1
#else
#define HAVE_DMA 0
#endif

// Kernel 1: per-block histograms. Data planes staged global->LDS via the
// async DMA path (global_load_lds, 16B/lane) — no VGPR-return slot per
// request, probing whether the DMA queue escapes the per-CU outstanding-
// read cap that pinned 12 prior configs at ~3.4 TB/s. Masks are ordinary
// cached loads issued while the DMA is in flight. 30 KB LDS -> 5 blocks/CU
// so barrier-drain latency overlaps across blocks. Math identical to R14.
__global__ void __launch_bounds__(256) hist_kernel(
        const float* __restrict__ inp,
        const float* __restrict__ tar,
        const float* __restrict__ msrc,
        const float* __restrict__ mtar,
        unsigned int* __restrict__ parts,
        unsigned int* __restrict__ tail) {
    __shared__ unsigned int hs[3 * NBINS];   // src packed count|fracsum
    __shared__ unsigned int ht[3 * NBINS];   // tar counts
#if HAVE_DMA
    __shared__ float buf[6][1024];           // 24 KB staging (6 planes x 4KB)
#endif
    for (int i = threadIdx.x; i < 3 * NBINS; i += blockDim.x) {
        hs[i] = 0u;
        ht[i] = 0u;
    }
    if (blockIdx.x == 0)
        for (int i = threadIdx.x; i < TAIL_WORDS; i += blockDim.x)
            tail[i] = 0u;
    __syncthreads();

    int nf[6] = {0, 0, 0, 0, 0, 0};   // v==255 counts (rows 0-2 src, 3-5 tar)

    const int stride = NBLK * 256;
    const int base0  = blockIdx.x * 256 + threadIdx.x;
#if HAVE_DMA
    const int wbase  = (threadIdx.x >> 6) * 256;   // wave-uniform LDS base
#endif

    #pragma unroll 1
    for (int it = 0; it < 4; ++it) {
        const int p4 = base0 + it * stride;        // this thread's float4 idx

#if HAVE_DMA
        // ---- issue async DMA for the 6 data planes (16 B per lane) ----
        #pragma unroll
        for (int s = 0; s < 3; ++s) {
            __builtin_amdgcn_global_load_lds(
                (const __attribute__((address_space(1))) void*)
                    (inp + (size_t)s * HH + (size_t)p4 * 4),
                (__attribute__((address_space(3))) void*)&buf[s][wbase],
                16, 0, 0);
            __builtin_amdgcn_global_load_lds(
                (const __attribute__((address_space(1))) void*)
                    (tar + (size_t)s * HH + (size_t)p4 * 4),
                (__attribute__((address_space(3))) void*)&buf[3 + s][wbase],
                16, 0, 0);
        }
#endif
        // masks: ordinary cached loads, overlap the DMA flight time
        const float4 ms4 = ((const float4*)msrc)[p4];
        const float4 mt4 = ((const float4*)mtar)[p4];
        const float mk[4] = {ms4.x, ms4.y, ms4.z, ms4.w};
        const float tk[4] = {mt4.x, mt4.y, mt4.z, mt4.w};

#if HAVE_DMA
        __syncthreads();   // drains vmcnt -> buf ready for all waves
#endif

        #pragma unroll
        for (int c = 0; c < 3; ++c) {
#if HAVE_DMA
            const float4 v4 = *(const float4*)&buf[c][threadIdx.x * 4];
            const float4 w4 = *(const float4*)&buf[3 + c][threadIdx.x * 4];
            const float vv[4] = {v4.x, v4.y, v4.z, v4.w};
            const float ww[4] = {w4.x, w4.y, w4.z, w4.w};
#else
            const floatx4 v4 = nt_load4(inp + (size_t)c * HH + (size_t)p4 * 4);
            const floatx4 w4 = nt_load4(tar + (size_t)c * HH + (size_t)p4 * 4);
            const float vv[4] = {v4[0], v4[1], v4[2], v4[3]};
            const float ww[4] = {w4[0], w4[1], w4[2], w4[3]};
#endif
            #pragma unroll
            for (int k = 0; k < 4; ++k) {
                // --- src: one packed atomic for mid bins ---
                {
                    const bool on = (mk[k] != 0.0f);
                    const float vr   = (vv[k] + 1.0f) * 0.5f;
                    const float v255 = fminf(fmaxf(vr, 0.0f), 1.0f) * 255.0f;
                    const bool hi = (v255 >= 255.0f);
                    const bool lo = (v255 <= 0.0f);
                    nf[c] += (int)(on && hi);
                    if (on && !lo && !hi) {
                        const int b = (int)v255;            // 0..254
                        const unsigned fx =
                            (unsigned)((v255 - (float)b) * FRAC_SCALE);
                        atomicAdd(&hs[c * NBINS + b], (1u << 20) | fx);
                    }
                }
                // --- tar: counts only ---
                {
                    const bool on = (tk[k] != 0.0f);
                    const float vr   = (ww[k] + 1.0f) * 0.5f;
                    const float v255 = fminf(fmaxf(vr, 0.0f), 1.0f) * 255.0f;
                    const bool hi = (v255 >= 255.0f);
                    const bool lo = (v255 <= 0.0f);
                    nf[3 + c] += (int)(on && hi);
                    if (on && !lo && !hi)
                        atomicAdd(&ht[c * NBINS + (int)v255], 1u);
                }
            }
        }

#if HAVE_DMA
        __syncthreads();   // all reads of buf done before next stage overwrites
#endif
    }

    // wave-reduce the 6 clip-255 counters, one LDS atomic per wave each
    const int lane = threadIdx.x & 63;
    #pragma unroll
    for (int j = 0; j < 6; ++j) {
        int f = nf[j];
        #pragma unroll
        for (int off = 32; off > 0; off >>= 1)
            f += __shfl_down(f, off, 64);
        if (lane == 0 && f) {
            if (j < 3) atomicAdd(&hs[j * NBINS + NBINS - 1], ((unsigned)f) << 20);
            else       atomicAdd(&ht[(j - 3) * NBINS + NBINS - 1], (unsigned)f);
        }
    }
    __syncthreads();

    // coalesced flush of this block's partial row (full overwrite -> no memset)
    unsigned int* row = parts + (size_t)blockIdx.x * ROW_DWORDS;
    for (int i = threadIdx.x; i < ROW_DWORDS; i += blockDim.x)
        row[i] = (i < 3 * NBINS) ? hs[i] : ht[i - 3 * NBINS];
}

// Kernel 2: column reduction over row-chunks; all-integer atomics
// (deterministic).
__global__ void reduce_kernel(const unsigned int* __restrict__ parts,
                              int* __restrict__ counts,      // [1536]
                              int* __restrict__ fracsI) {    // [768]
    const int j = blockIdx.x * blockDim.x + threadIdx.x;   // column 0..1535
    const int w0 = blockIdx.y * ROWS_PER_CHUNK;
    const int w1 = w0 + ROWS_PER_CHUNK;                    // NBLK % 32 == 0

    if (j < 768) {
        unsigned cnt = 0, fr = 0;
        for (int w = w0; w < w1; ++w) {
            const unsigned p = parts[(size_t)w * ROW_DWORDS + j];
            cnt += p >> 20;
            fr  += p & 0xFFFFFu;
        }
        if (cnt) atomicAdd(&counts[j], (int)cnt);
        if (fr)  atomicAdd(&fracsI[j], (int)fr);
    } else {
        unsigned cnt = 0;
        for (int w = w0; w < w1; ++w)
            cnt += parts[(size_t)w * ROW_DWORDS + j];
        if (cnt) atomicAdd(&counts[j], (int)cnt);
    }
}

// Kernel 3: derive n_0 per row (mask totals are exactly 2^20), cdf (bit-exact
// serial f32 cumsum), searchsorted table, analytic loss:
//   t <= b : sum = s_b - n_b*t ;  t >= b+1 : sum = n_b*t - s_b,
// with s_b = n_b*b + F_b, F_b = fracsI_b * 2^-12 (0 for clip bins).
__global__ void final_kernel(const int* __restrict__ counts,
                             const int* __restrict__ fracsI,
                             float* __restrict__ out) {
    __shared__ float cdf[6][NBINS];
    __shared__ int   lcnt[6 * NBINS];
    __shared__ double red[12];
    const int tid = threadIdx.x;           // 768 threads
    lcnt[tid]       = counts[tid];
    lcnt[tid + 768] = counts[tid + 768];
    __syncthreads();

    if (tid < 6) {
        // true n_0 = 2^20 - sum(b>=1); lcnt[..+0] holds only mid-bin-0 atomics
        int tot = 0;
        for (int i = 1; i < NBINS; ++i) tot += lcnt[tid * NBINS + i];
        lcnt[tid * NBINS + 0] = (1 << 20) - tot;
        // pdf = count / 2^20 is exact; serial f32 cumsum matches the reference
        float run = 0.0f;
        for (int i = 0; i < NBINS; ++i) {
            run += (float)lcnt[tid * NBINS + i] * (1.0f / KCNT);
            cdf[tid][i] = run;
        }
    }
    __syncthreads();

    const int c = tid >> 8, b = tid & (NBINS - 1);
    const float d = cdf[c][b];
    const float* r = cdf[3 + c];
    // searchsorted(r, d, side='left'): first j with r[j] >= d
    int lo = 0, hi = NBINS;
    while (lo < hi) {
        int mid = (lo + hi) >> 1;
        if (r[mid] < d) lo = mid + 1; else hi = mid;
    }
    int j = lo;
    if (j < 1) j = 1;
    if (j > NBINS - 1) j = NBINS - 1;
    bool valid = (r[j - 1] <= d) && (d <= r[j]);
    int t = valid ? j : b;
    if (b == NBINS - 1) t = NBINS - 1;

    const int n = lcnt[c * NBINS + b];
    const double s = (double)n * (double)b
                   + (double)fracsI[c * NBINS + b] * FRAC_INV;
    double contrib = (t <= b) ? (s - (double)n * (double)t)
                              : ((double)n * (double)t - s);

    #pragma unroll
    for (int off = 32; off > 0; off >>= 1)
        contrib += __shfl_down(contrib, off, 64);
    const int wave = tid >> 6, lane = tid & 63;
    if (lane == 0) red[wave] = contrib;
    __syncthreads();
    if (tid == 0) {
        double tot = 0.0;
        for (int w = 0; w < 12; ++w) tot += red[w];
        out[0] = (float)(tot / TOTAL_ELEMS);
    }
}

extern "C" void kernel_launch(void* const* d_in, const int* in_sizes, int n_in,
                              void* d_out, int out_size, void* d_ws, size_t ws_size,
                              hipStream_t stream) {
    const float* inp  = (const float*)d_in[0];   // (1,3,H,H)
    const float* tar  = (const float*)d_in[1];   // (1,3,H,H)
    const float* msrc = (const float*)d_in[2];   // (1,1,H,H)
    const float* mtar = (const float*)d_in[3];   // (1,1,H,H)
    float* out = (float*)d_out;

    char* ws = (char*)d_ws;
    unsigned int* parts  = (unsigned int*)ws;
    unsigned int* tail   = (unsigned int*)(ws + (size_t)NBLK * ROW_BYTES);
    int*          counts = (int*)tail;                 // [1536]
    int*          fracsI = (int*)(tail + 1536);        // [768]

    hist_kernel<<<NBLK, 256, 0, stream>>>(inp, tar, msrc, mtar, parts, tail);

    dim3 rgrid(ROW_DWORDS / 256, NBLK / ROWS_PER_CHUNK);   // 6 x 32 = 192
    reduce_kernel<<<rgrid, 256, 0, stream>>>(parts, counts, fracsI);
    final_kernel<<<1, 3 * NBINS, 0, stream>>>(counts, fracsI, out);
}